// Round 7
// baseline (427.593 us; speedup 1.0000x reference)
//
#include <hip/hip_runtime.h>
#include <hip/hip_bf16.h>

#define SIZE 6144
#define DDIM 2048
#define BHALF 2048
#define BIJ 4096
#define NT 48   // 6144 / 128 tiles per dim

typedef __attribute__((ext_vector_type(8))) short bf16x8;
typedef __attribute__((ext_vector_type(4))) float f32x4;
typedef __attribute__((ext_vector_type(4))) unsigned int u32x4;

__device__ __forceinline__ float block_reduce_sum(float v, float* red) {
    #pragma unroll
    for (int off = 32; off; off >>= 1) v += __shfl_xor(v, off, 64);
    int lane = threadIdx.x & 63, wid = threadIdx.x >> 6;
    if (lane == 0) red[wid] = v;
    __syncthreads();
    float t = red[0] + red[1] + red[2] + red[3];
    __syncthreads();
    return t;
}

// One block (256 thr) per row: L2-normalize in fp32, write bf16 z, and
// dii[r] = ||z_bf16[r]||^2 (fp32) so the diagonal exp term cancels
// consistently with the MFMA-computed sim[i,i].
__global__ __launch_bounds__(256) void normalize_kernel(
    const float* __restrict__ ei, const float* __restrict__ ej,
    const float* __restrict__ ek,
    unsigned short* __restrict__ zb, float* __restrict__ dii)
{
    __shared__ float red[4];
    int r = blockIdx.x;
    const float* src = (r < BHALF)   ? (ei + (size_t)r * DDIM)
                     : (r < 2*BHALF) ? (ej + (size_t)(r - BHALF) * DDIM)
                                     : (ek + (size_t)(r - 2*BHALF) * DDIM);
    int t = threadIdx.x;
    float4 v0 = ((const float4*)src)[t*2];
    float4 v1 = ((const float4*)src)[t*2 + 1];
    float ss = v0.x*v0.x + v0.y*v0.y + v0.z*v0.z + v0.w*v0.w
             + v1.x*v1.x + v1.y*v1.y + v1.z*v1.z + v1.w*v1.w;
    float tot = block_reduce_sum(ss, red);
    float scale = 1.0f / fmaxf(sqrtf(tot), 1e-12f);

    float xs[8] = {v0.x, v0.y, v0.z, v0.w, v1.x, v1.y, v1.z, v1.w};
    unsigned short u[8];
    float d = 0.f;
    #pragma unroll
    for (int j = 0; j < 8; ++j) {
        __hip_bfloat16 h = __float2bfloat16(xs[j] * scale);
        u[j] = *(unsigned short*)&h;
        float f = __bfloat162float(h);
        d += f * f;
    }
    *(u32x4*)&zb[(size_t)r * DDIM + t*8] = *(u32x4*)u;
    float dtot = block_reduce_sum(d, red);
    if (t == 0) dii[r] = dtot;
}

// R2-structure symmetric simexp, templated for ablation:
//   V=0: full (stage + compute + epilogue/atomics)   [production]
//   V=1: stage-only (gload_lds + barriers)
//   V=2: stage + compute (no epilogue; acc asm-kept)
//   V=3: compute-only (ds_read+MFMA on uninit LDS; acc asm-kept)
template<int V>
__global__ __launch_bounds__(256) void simexp_kernel(
    const unsigned short* __restrict__ zb, float* __restrict__ S)
{
    __shared__ short As[128 * 64];
    __shared__ short Bs[128 * 64];

    // triangular decode: bid -> (rt, ct), ct >= rt
    int rem = blockIdx.x;
    int rt = 0, width = NT;
    while (rem >= width) { rem -= width; ++rt; --width; }
    const int ct = rt + rem;

    const int tid  = threadIdx.x;
    const int lane = tid & 63;
    const int w    = tid >> 6;       // wave 0..3
    const int wr   = w >> 1, wc = w & 1;
    const int rowA0 = rt * 128, colB0 = ct * 128;

    const int rowc = lane >> 3;        // 0..7 (row within 8-row chunk)
    const int kc   = (lane & 7) * 8;   // bf16 col within BK=64

    f32x4 acc[4][4] = {};

    const int lr = lane & 15;
    const int kh = (lane >> 4) * 8;

    for (int kt = 0; kt < DDIM; kt += 64) {
        __syncthreads();
        if constexpr (V != 3) {
            #pragma unroll
            for (int it = 0; it < 4; ++it) {
                int rchunk = it * 32 + w * 8;   // wave-uniform LDS chunk base
                const unsigned short* ga =
                    zb + (size_t)(rowA0 + rchunk + rowc) * DDIM + kt + kc;
                __builtin_amdgcn_global_load_lds(
                    (const __attribute__((address_space(1))) void*)ga,
                    (__attribute__((address_space(3))) void*)&As[rchunk * 64],
                    16, 0, 0);
                const unsigned short* gb =
                    zb + (size_t)(colB0 + rchunk + rowc) * DDIM + kt + kc;
                __builtin_amdgcn_global_load_lds(
                    (const __attribute__((address_space(1))) void*)gb,
                    (__attribute__((address_space(3))) void*)&Bs[rchunk * 64],
                    16, 0, 0);
            }
        }
        __syncthreads();
        if constexpr (V != 1) {
            #pragma unroll
            for (int kk = 0; kk < 64; kk += 32) {
                bf16x8 af[4], bfr[4];
                #pragma unroll
                for (int mi = 0; mi < 4; ++mi)
                    af[mi] = *(const bf16x8*)&As[(wr*64 + mi*16 + lr)*64 + kk + kh];
                #pragma unroll
                for (int ni = 0; ni < 4; ++ni)
                    bfr[ni] = *(const bf16x8*)&Bs[(wc*64 + ni*16 + lr)*64 + kk + kh];
                #pragma unroll
                for (int mi = 0; mi < 4; ++mi)
                    #pragma unroll
                    for (int ni = 0; ni < 4; ++ni)
                        acc[mi][ni] = __builtin_amdgcn_mfma_f32_16x16x32_bf16(
                            af[mi], bfr[ni], acc[mi][ni], 0, 0, 0);
            }
        }
    }

    if constexpr (V == 1) return;

    if constexpr (V == 2 || V == 3) {
        // keep all MFMA results live without storing (rule #17)
        float keep = 0.f;
        #pragma unroll
        for (int mi = 0; mi < 4; ++mi)
            #pragma unroll
            for (int ni = 0; ni < 4; ++ni)
                #pragma unroll
                for (int q = 0; q < 4; ++q)
                    keep += acc[mi][ni][q];
        asm volatile("" :: "v"(keep));
        return;
    }

    // ---- V == 0: real epilogue
    #pragma unroll
    for (int mi = 0; mi < 4; ++mi)
        #pragma unroll
        for (int ni = 0; ni < 4; ++ni)
            #pragma unroll
            for (int q = 0; q < 4; ++q)
                acc[mi][ni][q] = __expf(10.0f * acc[mi][ni][q]);

    // row-sums: C/D row = (lane>>4)*4 + q (+mi*16), col = lane&15 (+ni*16)
    {
        float rs[4][4];
        #pragma unroll
        for (int mi = 0; mi < 4; ++mi)
            #pragma unroll
            for (int q = 0; q < 4; ++q) {
                float s = 0.f;
                #pragma unroll
                for (int ni = 0; ni < 4; ++ni) s += acc[mi][ni][q];
                rs[mi][q] = s;
            }
        #pragma unroll
        for (int off = 1; off < 16; off <<= 1)
            #pragma unroll
            for (int mi = 0; mi < 4; ++mi)
                #pragma unroll
                for (int q = 0; q < 4; ++q)
                    rs[mi][q] += __shfl_xor(rs[mi][q], off, 64);

        if ((lane & 15) == 0) {
            float* St = S + ((ct < BIJ / 128) ? 0 : SIZE);
            int rq = (lane >> 4) * 4;
            #pragma unroll
            for (int mi = 0; mi < 4; ++mi)
                #pragma unroll
                for (int q = 0; q < 4; ++q)
                    atomicAdd(&St[rowA0 + wr*64 + mi*16 + rq + q], rs[mi][q]);
        }
    }

    // col-sums (transpose contribution), off-diagonal tiles only
    if (rt != ct) {
        float cs[4];
        #pragma unroll
        for (int ni = 0; ni < 4; ++ni) {
            float s = 0.f;
            #pragma unroll
            for (int mi = 0; mi < 4; ++mi)
                #pragma unroll
                for (int q = 0; q < 4; ++q) s += acc[mi][ni][q];
            cs[ni] = s;
        }
        #pragma unroll
        for (int off = 16; off < 64; off <<= 1)
            #pragma unroll
            for (int ni = 0; ni < 4; ++ni)
                cs[ni] += __shfl_xor(cs[ni], off, 64);

        if (lane < 16) {
            float* St = S + ((rt < BIJ / 128) ? 0 : SIZE);
            #pragma unroll
            for (int ni = 0; ni < 4; ++ni)
                atomicAdd(&St[colB0 + wc*64 + ni*16 + lane], cs[ni]);
        }
    }
}

__global__ void zero_kernel(float* __restrict__ p, int n) {
    int i = blockIdx.x * 256 + threadIdx.x;
    if (i < n) p[i] = 0.f;
}

// Single block: per-row loss terms, total, write scalar.
__global__ __launch_bounds__(256) void loss_kernel(
    const float* __restrict__ S, const float* __restrict__ dii,
    float* __restrict__ out)
{
    __shared__ float red[4];
    float local = 0.f;
    const float c1 = logf((float)(BIJ - 1));
    const float c2 = logf((float)(BHALF - 1));
    for (int r = threadIdx.x; r < SIZE; r += 256) {
        float s1 = S[r], s2 = S[SIZE + r];
        float eii = __expf(10.0f * dii[r]);
        float denom = s1 + s2 - eii;
        float num, c;
        if (r < BIJ) { num = s1 - eii; c = c1; }
        else         { num = s2 - eii; c = c2; }
        local += logf(denom) - logf(num) + c;
    }
    float tot = block_reduce_sum(local, red);
    if (threadIdx.x == 0) out[0] = tot / (float)SIZE;
}

extern "C" void kernel_launch(void* const* d_in, const int* in_sizes, int n_in,
                              void* d_out, int out_size, void* d_ws, size_t ws_size,
                              hipStream_t stream) {
    const float* ei = (const float*)d_in[0];
    const float* ej = (const float*)d_in[1];
    const float* ek = (const float*)d_in[2];
    float* out = (float*)d_out;

    char* ws = (char*)d_ws;
    unsigned short* zb = (unsigned short*)ws;                    // 6144*2048*2 = 25165824 B
    float* dii = (float*)(ws + 25165824);                        // 24576 B
    float* S   = (float*)(ws + 25165824 + 24576);                // 2*6144*4 = 49152 B
    float* S2  = (float*)(ws + 25165824 + 24576 + 49152);        // 49152 B probe sink

    zero_kernel<<<dim3(48), dim3(256), 0, stream>>>(S, 2 * SIZE);
    normalize_kernel<<<dim3(SIZE), dim3(256), 0, stream>>>(ei, ej, ek, zb, dii);

    // ---- ablation probes (768 blocks = 3/CU, balanced; results discarded)
    simexp_kernel<1><<<dim3(768), dim3(256), 0, stream>>>(zb, S2);  // stage-only
    simexp_kernel<3><<<dim3(768), dim3(256), 0, stream>>>(zb, S2);  // compute-only
    simexp_kernel<2><<<dim3(768), dim3(256), 0, stream>>>(zb, S2);  // stage+compute
    simexp_kernel<0><<<dim3(768), dim3(256), 0, stream>>>(zb, S2);  // full, small grid

    // ---- production
    simexp_kernel<0><<<dim3(NT * (NT + 1) / 2), dim3(256), 0, stream>>>(zb, S);
    loss_kernel<<<dim3(1), dim3(256), 0, stream>>>(S, dii, out);
}

// Round 8
// 153.083 us; speedup vs baseline: 2.7932x; 2.7932x over previous
//
#include <hip/hip_runtime.h>
#include <hip/hip_bf16.h>

#define SIZE 6144
#define DDIM 2048
#define BHALF 2048
#define BIJ 4096
#define NT 48   // 6144 / 128 tiles per dim

typedef __attribute__((ext_vector_type(8))) short bf16x8;
typedef __attribute__((ext_vector_type(4))) float f32x4;
typedef __attribute__((ext_vector_type(4))) unsigned int u32x4;

__device__ __forceinline__ float block_reduce_sum(float v, float* red) {
    #pragma unroll
    for (int off = 32; off; off >>= 1) v += __shfl_xor(v, off, 64);
    int lane = threadIdx.x & 63, wid = threadIdx.x >> 6;
    if (lane == 0) red[wid] = v;
    __syncthreads();
    float t = red[0] + red[1] + red[2] + red[3];
    __syncthreads();
    return t;
}

// One block (256 thr) per row: L2-normalize in fp32, write bf16 z, and
// dii[r] = ||z_bf16[r]||^2 (fp32) so the diagonal exp term cancels
// consistently with the MFMA-computed sim[i,i].
__global__ __launch_bounds__(256) void normalize_kernel(
    const float* __restrict__ ei, const float* __restrict__ ej,
    const float* __restrict__ ek,
    unsigned short* __restrict__ zb, float* __restrict__ dii)
{
    __shared__ float red[4];
    int r = blockIdx.x;
    const float* src = (r < BHALF)   ? (ei + (size_t)r * DDIM)
                     : (r < 2*BHALF) ? (ej + (size_t)(r - BHALF) * DDIM)
                                     : (ek + (size_t)(r - 2*BHALF) * DDIM);
    int t = threadIdx.x;
    float4 v0 = ((const float4*)src)[t*2];
    float4 v1 = ((const float4*)src)[t*2 + 1];
    float ss = v0.x*v0.x + v0.y*v0.y + v0.z*v0.z + v0.w*v0.w
             + v1.x*v1.x + v1.y*v1.y + v1.z*v1.z + v1.w*v1.w;
    float tot = block_reduce_sum(ss, red);
    float scale = 1.0f / fmaxf(sqrtf(tot), 1e-12f);

    float xs[8] = {v0.x, v0.y, v0.z, v0.w, v1.x, v1.y, v1.z, v1.w};
    unsigned short u[8];
    float d = 0.f;
    #pragma unroll
    for (int j = 0; j < 8; ++j) {
        __hip_bfloat16 h = __float2bfloat16(xs[j] * scale);
        u[j] = *(unsigned short*)&h;
        float f = __bfloat162float(h);
        d += f * f;
    }
    *(u32x4*)&zb[(size_t)r * DDIM + t*8] = *(u32x4*)u;
    float dtot = block_reduce_sum(d, red);
    if (t == 0) dii[r] = dtot;
}

// Symmetric simexp, R2 schedule + XOR-swizzled LDS (rule #21 compliant):
// staging lane l reads global k-chunk ((l&7) ^ (l>>3)) of its row — SAME
// 128B segment per 8 lanes (coalescing identical to R2) — into the linear
// gload_lds destination. LDS [row][slot] thus holds global chunk
// (slot ^ (row&7)); reads fetch slot = j ^ (row&7). Each consecutive
// 8-lane group covers all 8 slots exactly once -> conflict-free b128.
__global__ __launch_bounds__(256) void simexp_kernel(
    const unsigned short* __restrict__ zb, float* __restrict__ S)
{
    __shared__ short As[128 * 64];
    __shared__ short Bs[128 * 64];

    // triangular decode: bid -> (rt, ct), ct >= rt
    int rem = blockIdx.x;
    int rt = 0, width = NT;
    while (rem >= width) { rem -= width; ++rt; --width; }
    const int ct = rt + rem;

    const int tid  = threadIdx.x;
    const int lane = tid & 63;
    const int w    = tid >> 6;       // wave 0..3
    const int wr   = w >> 1, wc = w & 1;
    const int rowA0 = rt * 128, colB0 = ct * 128;

    const int rowc = lane >> 3;                    // 0..7 (row within 8-row chunk)
    const int ksw  = (((lane & 7) ^ rowc)) * 8;    // swizzled bf16 chunk within BK=64

    f32x4 acc[4][4] = {};

    const int lr = lane & 15;
    const int l4 = lane >> 4;          // 0..3
    const int r7 = lr & 7;             // row&7 of every fragment row this lane reads

    for (int kt = 0; kt < DDIM; kt += 64) {
        __syncthreads();
        #pragma unroll
        for (int it = 0; it < 4; ++it) {
            int rchunk = it * 32 + w * 8;   // wave-uniform LDS chunk base
            const unsigned short* ga =
                zb + (size_t)(rowA0 + rchunk + rowc) * DDIM + kt + ksw;
            __builtin_amdgcn_global_load_lds(
                (const __attribute__((address_space(1))) void*)ga,
                (__attribute__((address_space(3))) void*)&As[rchunk * 64],
                16, 0, 0);
            const unsigned short* gb =
                zb + (size_t)(colB0 + rchunk + rowc) * DDIM + kt + ksw;
            __builtin_amdgcn_global_load_lds(
                (const __attribute__((address_space(1))) void*)gb,
                (__attribute__((address_space(3))) void*)&Bs[rchunk * 64],
                16, 0, 0);
        }
        __syncthreads();
        #pragma unroll
        for (int kk = 0; kk < 64; kk += 32) {
            const int j0 = kk >> 3;    // chunk base: 0 or 4
            const int eo = (((j0 + l4) ^ r7)) << 3;   // swizzled element offset
            bf16x8 af[4], bfr[4];
            #pragma unroll
            for (int mi = 0; mi < 4; ++mi)
                af[mi] = *(const bf16x8*)&As[(wr*64 + mi*16 + lr)*64 + eo];
            #pragma unroll
            for (int ni = 0; ni < 4; ++ni)
                bfr[ni] = *(const bf16x8*)&Bs[(wc*64 + ni*16 + lr)*64 + eo];
            #pragma unroll
            for (int mi = 0; mi < 4; ++mi)
                #pragma unroll
                for (int ni = 0; ni < 4; ++ni)
                    acc[mi][ni] = __builtin_amdgcn_mfma_f32_16x16x32_bf16(
                        af[mi], bfr[ni], acc[mi][ni], 0, 0, 0);
        }
    }

    // exp in-register (reused for both row- and col-sums)
    #pragma unroll
    for (int mi = 0; mi < 4; ++mi)
        #pragma unroll
        for (int ni = 0; ni < 4; ++ni)
            #pragma unroll
            for (int q = 0; q < 4; ++q)
                acc[mi][ni][q] = __expf(10.0f * acc[mi][ni][q]);

    // ---- row-sums: C/D row = (lane>>4)*4 + q (+mi*16), col = lane&15 (+ni*16)
    {
        float rs[4][4];
        #pragma unroll
        for (int mi = 0; mi < 4; ++mi)
            #pragma unroll
            for (int q = 0; q < 4; ++q) {
                float s = 0.f;
                #pragma unroll
                for (int ni = 0; ni < 4; ++ni) s += acc[mi][ni][q];
                rs[mi][q] = s;
            }
        #pragma unroll
        for (int off = 1; off < 16; off <<= 1)
            #pragma unroll
            for (int mi = 0; mi < 4; ++mi)
                #pragma unroll
                for (int q = 0; q < 4; ++q)
                    rs[mi][q] += __shfl_xor(rs[mi][q], off, 64);

        if ((lane & 15) == 0) {
            float* St = S + ((ct < BIJ / 128) ? 0 : SIZE);
            int rq = (lane >> 4) * 4;
            #pragma unroll
            for (int mi = 0; mi < 4; ++mi)
                #pragma unroll
                for (int q = 0; q < 4; ++q)
                    atomicAdd(&St[rowA0 + wr*64 + mi*16 + rq + q], rs[mi][q]);
        }
    }

    // ---- col-sums (transpose contribution), off-diagonal tiles only
    if (rt != ct) {
        float cs[4];
        #pragma unroll
        for (int ni = 0; ni < 4; ++ni) {
            float s = 0.f;
            #pragma unroll
            for (int mi = 0; mi < 4; ++mi)
                #pragma unroll
                for (int q = 0; q < 4; ++q) s += acc[mi][ni][q];
            cs[ni] = s;
        }
        #pragma unroll
        for (int off = 16; off < 64; off <<= 1)
            #pragma unroll
            for (int ni = 0; ni < 4; ++ni)
                cs[ni] += __shfl_xor(cs[ni], off, 64);

        if (lane < 16) {
            float* St = S + ((rt < BIJ / 128) ? 0 : SIZE);
            #pragma unroll
            for (int ni = 0; ni < 4; ++ni)
                atomicAdd(&St[colB0 + wc*64 + ni*16 + lane], cs[ni]);
        }
    }
}

__global__ void zero_kernel(float* __restrict__ p, int n) {
    int i = blockIdx.x * 256 + threadIdx.x;
    if (i < n) p[i] = 0.f;
}

// Single block: per-row loss terms, total, write scalar.
__global__ __launch_bounds__(256) void loss_kernel(
    const float* __restrict__ S, const float* __restrict__ dii,
    float* __restrict__ out)
{
    __shared__ float red[4];
    float local = 0.f;
    const float c1 = logf((float)(BIJ - 1));
    const float c2 = logf((float)(BHALF - 1));
    for (int r = threadIdx.x; r < SIZE; r += 256) {
        float s1 = S[r], s2 = S[SIZE + r];
        float eii = __expf(10.0f * dii[r]);
        float denom = s1 + s2 - eii;
        float num, c;
        if (r < BIJ) { num = s1 - eii; c = c1; }
        else         { num = s2 - eii; c = c2; }
        local += logf(denom) - logf(num) + c;
    }
    float tot = block_reduce_sum(local, red);
    if (threadIdx.x == 0) out[0] = tot / (float)SIZE;
}

extern "C" void kernel_launch(void* const* d_in, const int* in_sizes, int n_in,
                              void* d_out, int out_size, void* d_ws, size_t ws_size,
                              hipStream_t stream) {
    const float* ei = (const float*)d_in[0];
    const float* ej = (const float*)d_in[1];
    const float* ek = (const float*)d_in[2];
    float* out = (float*)d_out;

    char* ws = (char*)d_ws;
    unsigned short* zb = (unsigned short*)ws;                    // 6144*2048*2 = 25165824 B
    float* dii = (float*)(ws + 25165824);                        // 24576 B
    float* S   = (float*)(ws + 25165824 + 24576);                // 2*6144*4 = 49152 B

    zero_kernel<<<dim3(48), dim3(256), 0, stream>>>(S, 2 * SIZE);
    normalize_kernel<<<dim3(SIZE), dim3(256), 0, stream>>>(ei, ej, ek, zb, dii);
    simexp_kernel<<<dim3(NT * (NT + 1) / 2), dim3(256), 0, stream>>>(zb, S);
    loss_kernel<<<dim3(1), dim3(256), 0, stream>>>(S, dii, out);
}

// Round 9
// 152.386 us; speedup vs baseline: 2.8060x; 1.0046x over previous
//
#include <hip/hip_runtime.h>
#include <hip/hip_bf16.h>

#define SIZE 6144
#define DDIM 2048
#define BHALF 2048
#define BIJ 4096
#define NT 48   // 6144 / 128 tiles per dim

typedef __attribute__((ext_vector_type(8))) short bf16x8;
typedef __attribute__((ext_vector_type(4))) float f32x4;
typedef __attribute__((ext_vector_type(4))) unsigned int u32x4;

__device__ __forceinline__ float block_reduce_sum(float v, float* red) {
    #pragma unroll
    for (int off = 32; off; off >>= 1) v += __shfl_xor(v, off, 64);
    int lane = threadIdx.x & 63, wid = threadIdx.x >> 6;
    if (lane == 0) red[wid] = v;
    __syncthreads();
    float t = red[0] + red[1] + red[2] + red[3];
    __syncthreads();
    return t;
}

// One block (256 thr) per row: L2-normalize in fp32, write bf16 z, and
// dii[r] = ||z_bf16[r]||^2 (fp32) so the diagonal exp term cancels
// consistently with the MFMA-computed sim[i,i].
__global__ __launch_bounds__(256) void normalize_kernel(
    const float* __restrict__ ei, const float* __restrict__ ej,
    const float* __restrict__ ek,
    unsigned short* __restrict__ zb, float* __restrict__ dii)
{
    __shared__ float red[4];
    int r = blockIdx.x;
    const float* src = (r < BHALF)   ? (ei + (size_t)r * DDIM)
                     : (r < 2*BHALF) ? (ej + (size_t)(r - BHALF) * DDIM)
                                     : (ek + (size_t)(r - 2*BHALF) * DDIM);
    int t = threadIdx.x;
    float4 v0 = ((const float4*)src)[t*2];
    float4 v1 = ((const float4*)src)[t*2 + 1];
    float ss = v0.x*v0.x + v0.y*v0.y + v0.z*v0.z + v0.w*v0.w
             + v1.x*v1.x + v1.y*v1.y + v1.z*v1.z + v1.w*v1.w;
    float tot = block_reduce_sum(ss, red);
    float scale = 1.0f / fmaxf(sqrtf(tot), 1e-12f);

    float xs[8] = {v0.x, v0.y, v0.z, v0.w, v1.x, v1.y, v1.z, v1.w};
    unsigned short u[8];
    float d = 0.f;
    #pragma unroll
    for (int j = 0; j < 8; ++j) {
        __hip_bfloat16 h = __float2bfloat16(xs[j] * scale);
        u[j] = *(unsigned short*)&h;
        float f = __bfloat162float(h);
        d += f * f;
    }
    *(u32x4*)&zb[(size_t)r * DDIM + t*8] = *(u32x4*)u;
    float dtot = block_reduce_sum(d, red);
    if (t == 0) dii[r] = dtot;
}

// Symmetric simexp, R8 structure (XOR-swizzled LDS, zero-conflict b128,
// coalescing-preserving staging) + T1 XCD-aware job swizzle:
// 1176 triangular jobs = 24 row-pairs (p, 47-p) of exactly 49 jobs each.
// XCD x (= bid & 7; consecutive blockIdx round-robin XCDs on MI355X) owns
// pairs 3x+{0,1,2} -> 147 jobs/XCD, perfectly balanced, bijective
// (1176 % 8 == 0). Within an XCD consecutive jobs share the A row-panel
// (1 MB -> L2-resident) and sweep B panels sequentially, cutting L2-miss
// latency exposure on the per-iter barrier drain.
__global__ __launch_bounds__(256) void simexp_kernel(
    const unsigned short* __restrict__ zb, float* __restrict__ S)
{
    __shared__ short As[128 * 64];
    __shared__ short Bs[128 * 64];

    // XCD-aware triangular decode
    const int x  = blockIdx.x & 7;       // XCD
    const int j  = blockIdx.x >> 3;      // within-XCD job 0..146
    const int pi = j / 49;               // pair within XCD: 0..2
    const int jj = j % 49;               // job within pair: 0..48
    const int p  = 3 * x + pi;           // row-pair id 0..23
    int rt, ct;
    if (jj < 48 - p) { rt = p;      ct = p + jj; }            // row p: 48-p jobs
    else             { rt = 47 - p; ct = rt + (jj - (48 - p)); } // row 47-p: p+1 jobs

    const int tid  = threadIdx.x;
    const int lane = tid & 63;
    const int w    = tid >> 6;       // wave 0..3
    const int wr   = w >> 1, wc = w & 1;
    const int rowA0 = rt * 128, colB0 = ct * 128;

    const int rowc = lane >> 3;                    // 0..7 (row within 8-row chunk)
    const int ksw  = (((lane & 7) ^ rowc)) * 8;    // swizzled bf16 chunk within BK=64

    f32x4 acc[4][4] = {};

    const int lr = lane & 15;
    const int l4 = lane >> 4;          // 0..3
    const int r7 = lr & 7;             // row&7 of every fragment row this lane reads

    for (int kt = 0; kt < DDIM; kt += 64) {
        __syncthreads();
        #pragma unroll
        for (int it = 0; it < 4; ++it) {
            int rchunk = it * 32 + w * 8;   // wave-uniform LDS chunk base
            const unsigned short* ga =
                zb + (size_t)(rowA0 + rchunk + rowc) * DDIM + kt + ksw;
            __builtin_amdgcn_global_load_lds(
                (const __attribute__((address_space(1))) void*)ga,
                (__attribute__((address_space(3))) void*)&As[rchunk * 64],
                16, 0, 0);
            const unsigned short* gb =
                zb + (size_t)(colB0 + rchunk + rowc) * DDIM + kt + ksw;
            __builtin_amdgcn_global_load_lds(
                (const __attribute__((address_space(1))) void*)gb,
                (__attribute__((address_space(3))) void*)&Bs[rchunk * 64],
                16, 0, 0);
        }
        __syncthreads();
        #pragma unroll
        for (int kk = 0; kk < 64; kk += 32) {
            const int j0 = kk >> 3;    // chunk base: 0 or 4
            const int eo = (((j0 + l4) ^ r7)) << 3;   // swizzled element offset
            bf16x8 af[4], bfr[4];
            #pragma unroll
            for (int mi = 0; mi < 4; ++mi)
                af[mi] = *(const bf16x8*)&As[(wr*64 + mi*16 + lr)*64 + eo];
            #pragma unroll
            for (int ni = 0; ni < 4; ++ni)
                bfr[ni] = *(const bf16x8*)&Bs[(wc*64 + ni*16 + lr)*64 + eo];
            #pragma unroll
            for (int mi = 0; mi < 4; ++mi)
                #pragma unroll
                for (int ni = 0; ni < 4; ++ni)
                    acc[mi][ni] = __builtin_amdgcn_mfma_f32_16x16x32_bf16(
                        af[mi], bfr[ni], acc[mi][ni], 0, 0, 0);
        }
    }

    // exp in-register (reused for both row- and col-sums)
    #pragma unroll
    for (int mi = 0; mi < 4; ++mi)
        #pragma unroll
        for (int ni = 0; ni < 4; ++ni)
            #pragma unroll
            for (int q = 0; q < 4; ++q)
                acc[mi][ni][q] = __expf(10.0f * acc[mi][ni][q]);

    // ---- row-sums: C/D row = (lane>>4)*4 + q (+mi*16), col = lane&15 (+ni*16)
    {
        float rs[4][4];
        #pragma unroll
        for (int mi = 0; mi < 4; ++mi)
            #pragma unroll
            for (int q = 0; q < 4; ++q) {
                float s = 0.f;
                #pragma unroll
                for (int ni = 0; ni < 4; ++ni) s += acc[mi][ni][q];
                rs[mi][q] = s;
            }
        #pragma unroll
        for (int off = 1; off < 16; off <<= 1)
            #pragma unroll
            for (int mi = 0; mi < 4; ++mi)
                #pragma unroll
                for (int q = 0; q < 4; ++q)
                    rs[mi][q] += __shfl_xor(rs[mi][q], off, 64);

        if ((lane & 15) == 0) {
            float* St = S + ((ct < BIJ / 128) ? 0 : SIZE);
            int rq = (lane >> 4) * 4;
            #pragma unroll
            for (int mi = 0; mi < 4; ++mi)
                #pragma unroll
                for (int q = 0; q < 4; ++q)
                    atomicAdd(&St[rowA0 + wr*64 + mi*16 + rq + q], rs[mi][q]);
        }
    }

    // ---- col-sums (transpose contribution), off-diagonal tiles only
    if (rt != ct) {
        float cs[4];
        #pragma unroll
        for (int ni = 0; ni < 4; ++ni) {
            float s = 0.f;
            #pragma unroll
            for (int mi = 0; mi < 4; ++mi)
                #pragma unroll
                for (int q = 0; q < 4; ++q) s += acc[mi][ni][q];
            cs[ni] = s;
        }
        #pragma unroll
        for (int off = 16; off < 64; off <<= 1)
            #pragma unroll
            for (int ni = 0; ni < 4; ++ni)
                cs[ni] += __shfl_xor(cs[ni], off, 64);

        if (lane < 16) {
            float* St = S + ((rt < BIJ / 128) ? 0 : SIZE);
            #pragma unroll
            for (int ni = 0; ni < 4; ++ni)
                atomicAdd(&St[colB0 + wc*64 + ni*16 + lane], cs[ni]);
        }
    }
}

__global__ void zero_kernel(float* __restrict__ p, int n) {
    int i = blockIdx.x * 256 + threadIdx.x;
    if (i < n) p[i] = 0.f;
}

// Single block: per-row loss terms, total, write scalar.
__global__ __launch_bounds__(256) void loss_kernel(
    const float* __restrict__ S, const float* __restrict__ dii,
    float* __restrict__ out)
{
    __shared__ float red[4];
    float local = 0.f;
    const float c1 = logf((float)(BIJ - 1));
    const float c2 = logf((float)(BHALF - 1));
    for (int r = threadIdx.x; r < SIZE; r += 256) {
        float s1 = S[r], s2 = S[SIZE + r];
        float eii = __expf(10.0f * dii[r]);
        float denom = s1 + s2 - eii;
        float num, c;
        if (r < BIJ) { num = s1 - eii; c = c1; }
        else         { num = s2 - eii; c = c2; }
        local += logf(denom) - logf(num) + c;
    }
    float tot = block_reduce_sum(local, red);
    if (threadIdx.x == 0) out[0] = tot / (float)SIZE;
}

extern "C" void kernel_launch(void* const* d_in, const int* in_sizes, int n_in,
                              void* d_out, int out_size, void* d_ws, size_t ws_size,
                              hipStream_t stream) {
    const float* ei = (const float*)d_in[0];
    const float* ej = (const float*)d_in[1];
    const float* ek = (const float*)d_in[2];
    float* out = (float*)d_out;

    char* ws = (char*)d_ws;
    unsigned short* zb = (unsigned short*)ws;                    // 6144*2048*2 = 25165824 B
    float* dii = (float*)(ws + 25165824);                        // 24576 B
    float* S   = (float*)(ws + 25165824 + 24576);                // 2*6144*4 = 49152 B

    zero_kernel<<<dim3(48), dim3(256), 0, stream>>>(S, 2 * SIZE);
    normalize_kernel<<<dim3(SIZE), dim3(256), 0, stream>>>(ei, ej, ek, zb, dii);
    simexp_kernel<<<dim3(NT * (NT + 1) / 2), dim3(256), 0, stream>>>(zb, S);
    loss_kernel<<<dim3(1), dim3(256), 0, stream>>>(S, dii, out);
}

// Round 10
// 100.322 us; speedup vs baseline: 4.2622x; 1.5190x over previous
//
#include <hip/hip_runtime.h>
#include <hip/hip_bf16.h>
#include <hip/hip_fp8.h>

#define SIZE 6144
#define DDIM 2048
#define BHALF 2048
#define BIJ 4096
#define NT 48   // 6144 / 128 tiles per dim

typedef __attribute__((ext_vector_type(4))) float f32x4;
typedef __attribute__((ext_vector_type(4))) int i32x4;
typedef __attribute__((ext_vector_type(8))) int i32x8;

__device__ __forceinline__ float block_reduce_sum(float v, float* red) {
    #pragma unroll
    for (int off = 32; off; off >>= 1) v += __shfl_xor(v, off, 64);
    int lane = threadIdx.x & 63, wid = threadIdx.x >> 6;
    if (lane == 0) red[wid] = v;
    __syncthreads();
    float t = red[0] + red[1] + red[2] + red[3];
    __syncthreads();
    return t;
}

// One block (256 thr) per row: L2-normalize in fp32, write fp8-e4m3 of
// (z * 64)  (64 = 2^6; MX scale 2^-6 per operand dequants to z exactly),
// and dii[r] = ||z_q||^2 = sum(f^2)/4096 from the SAME quantized values so
// the diagonal exp term cancels consistently with the MFMA-computed sim[i,i].
__global__ __launch_bounds__(256) void normalize_kernel(
    const float* __restrict__ ei, const float* __restrict__ ej,
    const float* __restrict__ ek,
    unsigned char* __restrict__ zb, float* __restrict__ dii)
{
    __shared__ float red[4];
    int r = blockIdx.x;
    const float* src = (r < BHALF)   ? (ei + (size_t)r * DDIM)
                     : (r < 2*BHALF) ? (ej + (size_t)(r - BHALF) * DDIM)
                                     : (ek + (size_t)(r - 2*BHALF) * DDIM);
    int t = threadIdx.x;
    float4 v0 = ((const float4*)src)[t*2];
    float4 v1 = ((const float4*)src)[t*2 + 1];
    float ss = v0.x*v0.x + v0.y*v0.y + v0.z*v0.z + v0.w*v0.w
             + v1.x*v1.x + v1.y*v1.y + v1.z*v1.z + v1.w*v1.w;
    float tot = block_reduce_sum(ss, red);
    float scale = 64.0f / fmaxf(sqrtf(tot), 1e-12f);   // z * 64

    float xs[8] = {v0.x, v0.y, v0.z, v0.w, v1.x, v1.y, v1.z, v1.w};
    unsigned char u[8];
    float d = 0.f;
    #pragma unroll
    for (int j = 0; j < 8; ++j) {
        __hip_fp8_e4m3 h(xs[j] * scale);
        u[j] = h.__x;
        float f = (float)h;
        d += f * f;
    }
    *(unsigned long long*)&zb[(size_t)r * DDIM + t*8] = *(unsigned long long*)u;
    float dtot = block_reduce_sum(d, red);
    if (t == 0) dii[r] = dtot * (1.0f / 4096.0f);
}

// Symmetric simexp, R8 structure (XOR-swizzled LDS within the 128B
// coalescing granule, zero-conflict reads, XCD-aware triangular decode),
// ported to MX-fp8: BK=128 fp8 (= 128B/row window, same granule math as
// bf16 BK=64), mfma_scale_f32_16x16x128_f8f6f4 with E8M0 scale 0x79
// (2^-6 each operand -> /4096 = exact dequant of z*64). 16 K-iters.
__global__ __launch_bounds__(256) void simexp_kernel(
    const unsigned char* __restrict__ zb, float* __restrict__ S)
{
    __shared__ unsigned char As[128 * 128];   // 16 KiB
    __shared__ unsigned char Bs[128 * 128];   // 16 KiB

    // XCD-aware triangular decode (1176 = 24 row-pairs x 49 jobs; 8 XCDs x 147)
    const int x  = blockIdx.x & 7;
    const int j  = blockIdx.x >> 3;
    const int pi = j / 49;
    const int jj = j % 49;
    const int p  = 3 * x + pi;
    int rt, ct;
    if (jj < 48 - p) { rt = p;      ct = p + jj; }
    else             { rt = 47 - p; ct = rt + (jj - (48 - p)); }

    const int tid  = threadIdx.x;
    const int lane = tid & 63;
    const int w    = tid >> 6;       // wave 0..3
    const int wr   = w >> 1, wc = w & 1;
    const int rowA0 = rt * 128, colB0 = ct * 128;

    const int rowc = lane >> 3;                      // row within 8-row chunk
    const int ksw  = ((lane & 7) ^ rowc) * 16;       // swizzled 16B chunk (bytes)

    f32x4 acc[4][4] = {};

    const int lr = lane & 15;
    const int l4 = lane >> 4;          // 0..3
    const int r7 = lr & 7;

    for (int kt = 0; kt < DDIM; kt += 128) {
        __syncthreads();
        #pragma unroll
        for (int it = 0; it < 4; ++it) {
            int rchunk = it * 32 + w * 8;   // wave-uniform LDS chunk base
            const unsigned char* ga =
                zb + (size_t)(rowA0 + rchunk + rowc) * DDIM + kt + ksw;
            __builtin_amdgcn_global_load_lds(
                (const __attribute__((address_space(1))) void*)ga,
                (__attribute__((address_space(3))) void*)&As[rchunk * 128],
                16, 0, 0);
            const unsigned char* gb =
                zb + (size_t)(colB0 + rchunk + rowc) * DDIM + kt + ksw;
            __builtin_amdgcn_global_load_lds(
                (const __attribute__((address_space(1))) void*)gb,
                (__attribute__((address_space(3))) void*)&Bs[rchunk * 128],
                16, 0, 0);
        }
        __syncthreads();

        // A fragments: lane covers k-bytes [l4*32, l4*32+32) of its row,
        // i.e. chunks {2*l4, 2*l4+1}, stored at slots (chunk ^ (row&7)).
        i32x8 af[4];
        #pragma unroll
        for (int mi = 0; mi < 4; ++mi) {
            const int base = (wr*64 + mi*16 + lr) * 128;
            i32x4 lo = *(const i32x4*)&As[base + (((2*l4)    ^ r7) << 4)];
            i32x4 hi = *(const i32x4*)&As[base + (((2*l4 + 1) ^ r7) << 4)];
            af[mi] = __builtin_shufflevector(lo, hi, 0, 1, 2, 3, 4, 5, 6, 7);
        }
        #pragma unroll
        for (int ni = 0; ni < 4; ++ni) {
            const int base = (wc*64 + ni*16 + lr) * 128;
            i32x4 lo = *(const i32x4*)&Bs[base + (((2*l4)    ^ r7) << 4)];
            i32x4 hi = *(const i32x4*)&Bs[base + (((2*l4 + 1) ^ r7) << 4)];
            i32x8 bf = __builtin_shufflevector(lo, hi, 0, 1, 2, 3, 4, 5, 6, 7);
            #pragma unroll
            for (int mi = 0; mi < 4; ++mi)
                acc[mi][ni] = __builtin_amdgcn_mfma_scale_f32_16x16x128_f8f6f4(
                    af[mi], bf, acc[mi][ni], 0, 0,
                    0, 0x79797979, 0, 0x79797979);
        }
    }

    // exp in-register (reused for both row- and col-sums)
    #pragma unroll
    for (int mi = 0; mi < 4; ++mi)
        #pragma unroll
        for (int ni = 0; ni < 4; ++ni)
            #pragma unroll
            for (int q = 0; q < 4; ++q)
                acc[mi][ni][q] = __expf(10.0f * acc[mi][ni][q]);

    // ---- row-sums: C/D row = (lane>>4)*4 + q (+mi*16), col = lane&15 (+ni*16)
    {
        float rs[4][4];
        #pragma unroll
        for (int mi = 0; mi < 4; ++mi)
            #pragma unroll
            for (int q = 0; q < 4; ++q) {
                float s = 0.f;
                #pragma unroll
                for (int ni = 0; ni < 4; ++ni) s += acc[mi][ni][q];
                rs[mi][q] = s;
            }
        #pragma unroll
        for (int off = 1; off < 16; off <<= 1)
            #pragma unroll
            for (int mi = 0; mi < 4; ++mi)
                #pragma unroll
                for (int q = 0; q < 4; ++q)
                    rs[mi][q] += __shfl_xor(rs[mi][q], off, 64);

        if ((lane & 15) == 0) {
            float* St = S + ((ct < BIJ / 128) ? 0 : SIZE);
            int rq = l4 * 4;
            #pragma unroll
            for (int mi = 0; mi < 4; ++mi)
                #pragma unroll
                for (int q = 0; q < 4; ++q)
                    atomicAdd(&St[rowA0 + wr*64 + mi*16 + rq + q], rs[mi][q]);
        }
    }

    // ---- col-sums (transpose contribution), off-diagonal tiles only
    if (rt != ct) {
        float cs[4];
        #pragma unroll
        for (int ni = 0; ni < 4; ++ni) {
            float s = 0.f;
            #pragma unroll
            for (int mi = 0; mi < 4; ++mi)
                #pragma unroll
                for (int q = 0; q < 4; ++q) s += acc[mi][ni][q];
            cs[ni] = s;
        }
        #pragma unroll
        for (int off = 16; off < 64; off <<= 1)
            #pragma unroll
            for (int ni = 0; ni < 4; ++ni)
                cs[ni] += __shfl_xor(cs[ni], off, 64);

        if (lane < 16) {
            float* St = S + ((rt < BIJ / 128) ? 0 : SIZE);
            #pragma unroll
            for (int ni = 0; ni < 4; ++ni)
                atomicAdd(&St[colB0 + wc*64 + ni*16 + lane], cs[ni]);
        }
    }
}

__global__ void zero_kernel(float* __restrict__ p, int n) {
    int i = blockIdx.x * 256 + threadIdx.x;
    if (i < n) p[i] = 0.f;
}

// Single block: per-row loss terms, total, write scalar.
__global__ __launch_bounds__(256) void loss_kernel(
    const float* __restrict__ S, const float* __restrict__ dii,
    float* __restrict__ out)
{
    __shared__ float red[4];
    float local = 0.f;
    const float c1 = logf((float)(BIJ - 1));
    const float c2 = logf((float)(BHALF - 1));
    for (int r = threadIdx.x; r < SIZE; r += 256) {
        float s1 = S[r], s2 = S[SIZE + r];
        float eii = __expf(10.0f * dii[r]);
        float denom = s1 + s2 - eii;
        float num, c;
        if (r < BIJ) { num = s1 - eii; c = c1; }
        else         { num = s2 - eii; c = c2; }
        local += logf(denom) - logf(num) + c;
    }
    float tot = block_reduce_sum(local, red);
    if (threadIdx.x == 0) out[0] = tot / (float)SIZE;
}

extern "C" void kernel_launch(void* const* d_in, const int* in_sizes, int n_in,
                              void* d_out, int out_size, void* d_ws, size_t ws_size,
                              hipStream_t stream) {
    const float* ei = (const float*)d_in[0];
    const float* ej = (const float*)d_in[1];
    const float* ek = (const float*)d_in[2];
    float* out = (float*)d_out;

    char* ws = (char*)d_ws;
    unsigned char* zb = (unsigned char*)ws;                      // 6144*2048*1 = 12582912 B
    float* dii = (float*)(ws + 12582912);                        // 24576 B
    float* S   = (float*)(ws + 12582912 + 24576);                // 2*6144*4 = 49152 B

    zero_kernel<<<dim3(48), dim3(256), 0, stream>>>(S, 2 * SIZE);
    normalize_kernel<<<dim3(SIZE), dim3(256), 0, stream>>>(ei, ej, ek, zb, dii);
    simexp_kernel<<<dim3(NT * (NT + 1) / 2), dim3(256), 0, stream>>>(zb, S);
    loss_kernel<<<dim3(1), dim3(256), 0, stream>>>(S, dii, out);
}

// Round 11
// 91.699 us; speedup vs baseline: 4.6630x; 1.0940x over previous
//
#include <hip/hip_runtime.h>
#include <hip/hip_bf16.h>
#include <hip/hip_fp8.h>

#define SIZE 6144
#define DDIM 2048
#define BHALF 2048
#define BIJ 4096
#define NT 48   // 6144 / 128 tiles per dim

typedef __attribute__((ext_vector_type(4))) float f32x4;
typedef __attribute__((ext_vector_type(4))) int i32x4;
typedef __attribute__((ext_vector_type(8))) int i32x8;

__device__ __forceinline__ float block_reduce_sum(float v, float* red) {
    #pragma unroll
    for (int off = 32; off; off >>= 1) v += __shfl_xor(v, off, 64);
    int lane = threadIdx.x & 63, wid = threadIdx.x >> 6;
    if (lane == 0) red[wid] = v;
    __syncthreads();
    float t = red[0] + red[1] + red[2] + red[3];
    __syncthreads();
    return t;
}

// One block (256 thr) per row: L2-normalize in fp32, write fp8-e4m3 of
// (z * 64)  (MX scale 2^-6 per operand dequants to z exactly), and
// dii[r] = ||z_q||^2 from the SAME quantized values so the diagonal exp
// term cancels consistently. Blocks 0..47 also zero the S accumulator
// (S is only read/atomicAdd'd by later kernels on this stream).
__global__ __launch_bounds__(256) void normalize_kernel(
    const float* __restrict__ ei, const float* __restrict__ ej,
    const float* __restrict__ ek,
    unsigned char* __restrict__ zb, float* __restrict__ dii,
    float* __restrict__ S)
{
    __shared__ float red[4];
    int r = blockIdx.x;
    if (r < 48) S[r * 256 + threadIdx.x] = 0.f;   // 48*256 = 2*SIZE
    const float* src = (r < BHALF)   ? (ei + (size_t)r * DDIM)
                     : (r < 2*BHALF) ? (ej + (size_t)(r - BHALF) * DDIM)
                                     : (ek + (size_t)(r - 2*BHALF) * DDIM);
    int t = threadIdx.x;
    float4 v0 = ((const float4*)src)[t*2];
    float4 v1 = ((const float4*)src)[t*2 + 1];
    float ss = v0.x*v0.x + v0.y*v0.y + v0.z*v0.z + v0.w*v0.w
             + v1.x*v1.x + v1.y*v1.y + v1.z*v1.z + v1.w*v1.w;
    float tot = block_reduce_sum(ss, red);
    float scale = 64.0f / fmaxf(sqrtf(tot), 1e-12f);   // z * 64

    float xs[8] = {v0.x, v0.y, v0.z, v0.w, v1.x, v1.y, v1.z, v1.w};
    unsigned char u[8];
    float d = 0.f;
    #pragma unroll
    for (int j = 0; j < 8; ++j) {
        __hip_fp8_e4m3 h(xs[j] * scale);
        u[j] = h.__x;
        float f = (float)h;
        d += f * f;
    }
    *(unsigned long long*)&zb[(size_t)r * DDIM + t*8] = *(unsigned long long*)u;
    float dtot = block_reduce_sum(d, red);
    if (t == 0) dii[r] = dtot * (1.0f / 4096.0f);
}

// Symmetric simexp, MX-fp8 (BK=128, mfma_scale 16x16x128, scale 0x79 = 2^-6
// per operand), XOR-swizzled LDS within the 128B coalescing granule,
// XCD-aware triangular decode, and T3-minimum double-buffered prefetch:
// issue next K-tile's global_load_lds BEFORE consuming the current tile;
// one __syncthreads() per K-iter (its compiler-emitted vmcnt(0)/lgkmcnt(0)
// drain lands AFTER ~550cy of ds_read+MFMA, hiding the load latency).
// Hazards: RAW (stage t+1 -> read t+1) and WAR (stage t+1 overwrites buf
// read at t) both protected by the end-of-iter barrier drain.
__global__ __launch_bounds__(256) void simexp_kernel(
    const unsigned char* __restrict__ zb, float* __restrict__ S)
{
    __shared__ unsigned char As[2][128 * 128];   // 2 x 16 KiB
    __shared__ unsigned char Bs[2][128 * 128];   // 2 x 16 KiB

    // XCD-aware triangular decode (1176 = 24 row-pairs x 49 jobs; 8 XCDs x 147)
    const int x  = blockIdx.x & 7;
    const int j  = blockIdx.x >> 3;
    const int pi = j / 49;
    const int jj = j % 49;
    const int p  = 3 * x + pi;
    int rt, ct;
    if (jj < 48 - p) { rt = p;      ct = p + jj; }
    else             { rt = 47 - p; ct = rt + (jj - (48 - p)); }

    const int tid  = threadIdx.x;
    const int lane = tid & 63;
    const int w    = tid >> 6;       // wave 0..3
    const int wr   = w >> 1, wc = w & 1;
    const int rowA0 = rt * 128, colB0 = ct * 128;

    const int rowc = lane >> 3;                      // row within 8-row chunk
    const int ksw  = ((lane & 7) ^ rowc) * 16;       // swizzled 16B chunk (bytes)

    f32x4 acc[4][4] = {};

    const int lr = lane & 15;
    const int l4 = lane >> 4;          // 0..3
    const int r7 = lr & 7;

#define STAGE(buf, kb) do {                                                  \
    _Pragma("unroll")                                                        \
    for (int it = 0; it < 4; ++it) {                                         \
        int rchunk = it * 32 + w * 8;   /* wave-uniform LDS chunk base */    \
        const unsigned char* ga =                                            \
            zb + (size_t)(rowA0 + rchunk + rowc) * DDIM + (kb) + ksw;        \
        __builtin_amdgcn_global_load_lds(                                    \
            (const __attribute__((address_space(1))) void*)ga,               \
            (__attribute__((address_space(3))) void*)&As[buf][rchunk * 128], \
            16, 0, 0);                                                       \
        const unsigned char* gb =                                            \
            zb + (size_t)(colB0 + rchunk + rowc) * DDIM + (kb) + ksw;        \
        __builtin_amdgcn_global_load_lds(                                    \
            (const __attribute__((address_space(1))) void*)gb,               \
            (__attribute__((address_space(3))) void*)&Bs[buf][rchunk * 128], \
            16, 0, 0);                                                       \
    }                                                                        \
} while (0)

    // prologue: stage K-tile 0 into buf 0, drain, barrier
    STAGE(0, 0);
    __syncthreads();

    for (int t = 0; t < 16; ++t) {
        const int cur = t & 1;
        if (t < 15) STAGE(cur ^ 1, (t + 1) * 128);   // prefetch next tile

        // A fragments: lane covers k-bytes [l4*32, l4*32+32) of its row,
        // i.e. chunks {2*l4, 2*l4+1}, stored at slots (chunk ^ (row&7)).
        i32x8 af[4];
        #pragma unroll
        for (int mi = 0; mi < 4; ++mi) {
            const int base = (wr*64 + mi*16 + lr) * 128;
            i32x4 lo = *(const i32x4*)&As[cur][base + (((2*l4)     ^ r7) << 4)];
            i32x4 hi = *(const i32x4*)&As[cur][base + (((2*l4 + 1) ^ r7) << 4)];
            af[mi] = __builtin_shufflevector(lo, hi, 0, 1, 2, 3, 4, 5, 6, 7);
        }
        #pragma unroll
        for (int ni = 0; ni < 4; ++ni) {
            const int base = (wc*64 + ni*16 + lr) * 128;
            i32x4 lo = *(const i32x4*)&Bs[cur][base + (((2*l4)     ^ r7) << 4)];
            i32x4 hi = *(const i32x4*)&Bs[cur][base + (((2*l4 + 1) ^ r7) << 4)];
            i32x8 bf = __builtin_shufflevector(lo, hi, 0, 1, 2, 3, 4, 5, 6, 7);
            #pragma unroll
            for (int mi = 0; mi < 4; ++mi)
                acc[mi][ni] = __builtin_amdgcn_mfma_scale_f32_16x16x128_f8f6f4(
                    af[mi], bf, acc[mi][ni], 0, 0,
                    0, 0x79797979, 0, 0x79797979);
        }

        if (t < 15) __syncthreads();   // drains vmcnt(0)+lgkmcnt(0): next buf
                                       // ready, current buf safe to overwrite
    }

    // exp in-register (reused for both row- and col-sums)
    #pragma unroll
    for (int mi = 0; mi < 4; ++mi)
        #pragma unroll
        for (int ni = 0; ni < 4; ++ni)
            #pragma unroll
            for (int q = 0; q < 4; ++q)
                acc[mi][ni][q] = __expf(10.0f * acc[mi][ni][q]);

    // ---- row-sums: C/D row = (lane>>4)*4 + q (+mi*16), col = lane&15 (+ni*16)
    {
        float rs[4][4];
        #pragma unroll
        for (int mi = 0; mi < 4; ++mi)
            #pragma unroll
            for (int q = 0; q < 4; ++q) {
                float s = 0.f;
                #pragma unroll
                for (int ni = 0; ni < 4; ++ni) s += acc[mi][ni][q];
                rs[mi][q] = s;
            }
        #pragma unroll
        for (int off = 1; off < 16; off <<= 1)
            #pragma unroll
            for (int mi = 0; mi < 4; ++mi)
                #pragma unroll
                for (int q = 0; q < 4; ++q)
                    rs[mi][q] += __shfl_xor(rs[mi][q], off, 64);

        if ((lane & 15) == 0) {
            float* St = S + ((ct < BIJ / 128) ? 0 : SIZE);
            int rq = l4 * 4;
            #pragma unroll
            for (int mi = 0; mi < 4; ++mi)
                #pragma unroll
                for (int q = 0; q < 4; ++q)
                    atomicAdd(&St[rowA0 + wr*64 + mi*16 + rq + q], rs[mi][q]);
        }
    }

    // ---- col-sums (transpose contribution), off-diagonal tiles only
    if (rt != ct) {
        float cs[4];
        #pragma unroll
        for (int ni = 0; ni < 4; ++ni) {
            float s = 0.f;
            #pragma unroll
            for (int mi = 0; mi < 4; ++mi)
                #pragma unroll
                for (int q = 0; q < 4; ++q) s += acc[mi][ni][q];
            cs[ni] = s;
        }
        #pragma unroll
        for (int off = 16; off < 64; off <<= 1)
            #pragma unroll
            for (int ni = 0; ni < 4; ++ni)
                cs[ni] += __shfl_xor(cs[ni], off, 64);

        if (lane < 16) {
            float* St = S + ((rt < BIJ / 128) ? 0 : SIZE);
            #pragma unroll
            for (int ni = 0; ni < 4; ++ni)
                atomicAdd(&St[colB0 + wc*64 + ni*16 + lane], cs[ni]);
        }
    }
}

// Single block: per-row loss terms, total, write scalar.
__global__ __launch_bounds__(256) void loss_kernel(
    const float* __restrict__ S, const float* __restrict__ dii,
    float* __restrict__ out)
{
    __shared__ float red[4];
    float local = 0.f;
    const float c1 = logf((float)(BIJ - 1));
    const float c2 = logf((float)(BHALF - 1));
    for (int r = threadIdx.x; r < SIZE; r += 256) {
        float s1 = S[r], s2 = S[SIZE + r];
        float eii = __expf(10.0f * dii[r]);
        float denom = s1 + s2 - eii;
        float num, c;
        if (r < BIJ) { num = s1 - eii; c = c1; }
        else         { num = s2 - eii; c = c2; }
        local += logf(denom) - logf(num) + c;
    }
    float tot = block_reduce_sum(local, red);
    if (threadIdx.x == 0) out[0] = tot / (float)SIZE;
}

extern "C" void kernel_launch(void* const* d_in, const int* in_sizes, int n_in,
                              void* d_out, int out_size, void* d_ws, size_t ws_size,
                              hipStream_t stream) {
    const float* ei = (const float*)d_in[0];
    const float* ej = (const float*)d_in[1];
    const float* ek = (const float*)d_in[2];
    float* out = (float*)d_out;

    char* ws = (char*)d_ws;
    unsigned char* zb = (unsigned char*)ws;                      // 6144*2048*1 = 12582912 B
    float* dii = (float*)(ws + 12582912);                        // 24576 B
    float* S   = (float*)(ws + 12582912 + 24576);                // 2*6144*4 = 49152 B

    normalize_kernel<<<dim3(SIZE), dim3(256), 0, stream>>>(ei, ej, ek, zb, dii, S);
    simexp_kernel<<<dim3(NT * (NT + 1) / 2), dim3(256), 0, stream>>>(zb, S);
    loss_kernel<<<dim3(1), dim3(256), 0, stream>>>(S, dii, out);
}